// Round 12
// baseline (269.259 us; speedup 1.0000x reference)
//
#include <hip/hip_runtime.h>
#include <math.h>

// B=16, C_IN=256, C_OUT=256, H=W=64, K=3, NK=2
// weights: [2][256][256][3][3]; bank stride 589824 floats; per-o stride 2304.
//
// Pipeline (3 kernels):
//  1. wprep: combined+modulated+demod bf16 weights -> wq, 32x32-MFMA LDS image
//     per (b,c16): [tap9][oh2][mf4][lane64][e8] (36864 ush = 73728 B), where
//     A-frag: o = oh*128 + mf*32 + (lane&31), i = c*16 + (lane>>5)*8 + e.
//  2. xprep: x -> bf16 xq [b][c16][rowp66][colp66][i16], halo zeros, PLAIN
//     layout (32x32 B-reads are conflict-free without swizzle).
//  3. conv_fused: implicit GEMM via mfma_f32_32x32x16_bf16 (K=16 = 2 i-octets
//     per tap; 9 taps = 9 MFMAs, no dummy). Block 256 thr (4 waves) =
//     256 o x 4 rows x 64 px; wave = (oh, pq) tile 128o x 128px, mf4 x nf4,
//     acc 256 f32. A single-buffered in 2 rolling halves (taps0-3 / taps4-8),
//     x double-buffered; counted vmcnt gates; P/Q frag ping-pong across taps.
//     Epilogue: fused channel RMSNorm * gamma * 16 + SiLU (norm kernel gone).

typedef __attribute__((ext_vector_type(8))) short short8;
typedef __attribute__((ext_vector_type(16))) float f32x16;

#define GLL16(src, dst)                                                       \
  __builtin_amdgcn_global_load_lds(                                           \
      (const __attribute__((address_space(1))) unsigned int*)(src),           \
      (__attribute__((address_space(3))) unsigned int*)(dst), 16, 0, 0)

static __device__ __forceinline__ unsigned short f2bf(float v) {
  union { float f; unsigned u; } u;
  u.f = v;
  unsigned r = u.u + 0x7FFF + ((u.u >> 16) & 1);  // RNE
  return (unsigned short)(r >> 16);
}

// ---------------------------------------------------------------------------
// Kernel 1: fused weight prep. Grid 512 = b(16) x oq(32 o-octets), 256 thr.
// Thread t: o = oq*8 + (t>>5); its = t&31 -> c = its>>1, io = its&1.
// ---------------------------------------------------------------------------
__global__ __launch_bounds__(256) void wprep(
    const float* __restrict__ mod, const float* __restrict__ kmod,
    const float* __restrict__ weights, unsigned short* __restrict__ wq) {
  int blk = blockIdx.x;  // b*32 + oq
  int b = blk >> 5, oq = blk & 31;
  int t = threadIdx.x;
  int o_l = t >> 5, its = t & 31;
  int o = oq * 8 + o_l;

  float k0 = kmod[b * 2 + 0], k1 = kmod[b * 2 + 1];
  float mx = fmaxf(k0, k1);
  float e0 = expf(k0 - mx), e1 = expf(k1 - mx);
  float ai = 1.0f / (e0 + e1);
  float a0 = e0 * ai, a1 = e1 * ai;

  float wv[9][8];  // [j][e]
  float s = 0.0f;
  const float* w0 = &weights[((size_t)o * 256 + its * 8) * 9];
  const float* w1 = w0 + 589824;
#pragma unroll
  for (int e = 0; e < 8; ++e) {
    float f = mod[b * 256 + its * 8 + e] + 1.0f;
#pragma unroll
    for (int j = 0; j < 9; ++j) {
      float v = (a0 * w0[e * 9 + j] + a1 * w1[e * 9 + j]) * f;
      wv[j][e] = v;
      s = fmaf(v, v, s);
    }
  }

  __shared__ float red[8][32];
  __shared__ float scl[8];
  red[o_l][its] = s;
  __syncthreads();
  if (t < 8) {
    float tot = 0.0f;
#pragma unroll
    for (int k = 0; k < 32; ++k) tot += red[t][k];
    scl[t] = rsqrtf(fmaxf(tot, 1e-8f));
  }
  __syncthreads();
  float sc = scl[o_l];

  int c = its >> 1, io = its & 1;
  int oh = o >> 7, mf = (o >> 5) & 3;
  int lane2 = (o & 31) + io * 32;
  // chunk [tap9][oh2][mf4][lane64][e8] ush per (b,c)
  size_t cbase = ((size_t)(b * 16 + c)) * 36864 + oh * 2048 + mf * 512 + lane2 * 8;
#pragma unroll
  for (int j = 0; j < 9; ++j) {
    short8 pk;
#pragma unroll
    for (int e = 0; e < 8; ++e) pk[e] = (short)f2bf(wv[j][e] * sc);
    *(short8*)(wq + cbase + j * 4096) = pk;
  }
}

// ---------------------------------------------------------------------------
// Kernel 2: x prep -> bf16 xq [b][c][rowp66][colp66][i16], halo zeroed, plain.
// ---------------------------------------------------------------------------
__global__ __launch_bounds__(256) void xprep(
    const float* __restrict__ x, unsigned short* __restrict__ xq) {
  int blk = blockIdx.x;  // (b*16 + c)*66 + rowp
  int rowp = blk % 66;
  int bc = blk / 66;
  int b = bc >> 4, c = bc & 15;
  int t = threadIdx.x;
  size_t obase = (size_t)blk * 1056;

  if (rowp == 0 || rowp == 65) {
    for (int idx = t; idx < 1056; idx += 256) xq[obase + idx] = 0;
    return;
  }
  __shared__ __align__(16) unsigned short xs2[1056];
  int row = rowp - 1;
  for (int idx = t; idx < 1056; idx += 256) xs2[idx] = 0;
  __syncthreads();
#pragma unroll
  for (int k = 0; k < 4; ++k) {
    int idx = t + k * 256;  // 0..1023
    int il = idx >> 6, col = idx & 63;
    float v = x[(((size_t)b * 256 + c * 16 + il) * 64 + row) * 64 + col];
    xs2[(col + 1) * 16 + il] = f2bf(v);
  }
  __syncthreads();
  if (t < 132) *(short8*)(xq + obase + (size_t)t * 8) = *(const short8*)&xs2[t * 8];
}

// ---------------------------------------------------------------------------
// Kernel 3: fused conv + RMSNorm + SiLU. Grid 256 (XCD-clustered), 256 thr.
// ---------------------------------------------------------------------------
__global__ __launch_bounds__(256, 1) void conv_fused(
    const unsigned short* __restrict__ xq, const unsigned short* __restrict__ wq,
    const float* __restrict__ gamma, float* __restrict__ out) {
  __shared__ __align__(16) unsigned short wsm[36864];    // 73728 B, [tap][oh][mf][lane][e]
  __shared__ __align__(16) unsigned short xsm[2][8192];  // 16384 B each
  __shared__ float redl[1024];                           // [adder4][px256]
  __shared__ float invs[256];
  __shared__ float gsm[256];

  int bid = blockIdx.x;
  int xcd = bid & 7;
  int kk = bid >> 3;            // 0..31
  int b = xcd * 2 + (kk >> 4);  // 2 batches per XCD
  int rt = kk & 15;             // 4-row tile
  int r0 = rt * 4;

  int t = threadIdx.x;
  int w = t >> 6, lane = t & 63;
  int oh = w >> 1, pq = w & 1;
  int l31 = lane & 31, l5 = lane >> 5;

  gsm[t] = gamma[t];

  // A base: + imm(tap*8192 + mf*1024) at use
  const char* aw = (const char*)wsm + oh * 4096 + lane * 16;
  // B bases per x-buffer: + imm(kh*2112 + kw*32 + r*2112 + h*1024) at use
  const char* xb0 = (const char*)xsm[0] + ((2 * pq) * 66 + l31) * 32 + l5 * 16;
  const char* xb1 = (const char*)xsm[1] + ((2 * pq) * 66 + l31) * 32 + l5 * 16;

  f32x16 acc[4][4];
#pragma unroll
  for (int mf = 0; mf < 4; ++mf)
#pragma unroll
    for (int nf = 0; nf < 4; ++nf)
#pragma unroll
      for (int q = 0; q < 16; ++q) acc[mf][nf][q] = 0.f;

  // ---- staging macros ----
#define GLLL(cn)                                                               \
  _Pragma("unroll") for (int r = 0; r < 8; ++r) {                              \
    GLL16(wq + ((size_t)(b * 16 + (cn))) * 36864 + (r * 256 + t) * 8,          \
          &wsm[(r * 256 + t) * 8]);                                            \
  }
#define GLLH(cn)                                                               \
  _Pragma("unroll") for (int r = 0; r < 10; ++r) {                             \
    GLL16(wq + ((size_t)(b * 16 + (cn))) * 36864 + 16384 + (r * 256 + t) * 8,  \
          &wsm[16384 + (r * 256 + t) * 8]);                                    \
  }
#define GLLX(cn, nb)                                                           \
  _Pragma("unroll") for (int r = 0; r < 4; ++r) {                              \
    GLL16(xq + ((size_t)((b * 16 + (cn)) * 66 + r0)) * 1056 + (r * 256 + t) * 8, \
          &xsm[nb][(r * 256 + t) * 8]);                                        \
  }

  short8 PA[4], PB[4], QA[4], QB[4];

#define DSRD(SA, SB, TAP, XB)                                                  \
  {                                                                            \
    _Pragma("unroll") for (int mf = 0; mf < 4; ++mf)                           \
        SA[mf] = *(const short8*)(aw + (TAP) * 8192 + mf * 1024);              \
    const char* xb_ = (XB) ? xb1 : xb0;                                        \
    _Pragma("unroll") for (int r = 0; r < 2; ++r)                              \
        _Pragma("unroll") for (int h = 0; h < 2; ++h)                          \
            SB[r * 2 + h] = *(const short8*)(xb_ + ((TAP) / 3) * 2112 +        \
                                             ((TAP) % 3) * 32 + r * 2112 +     \
                                             h * 1024);                        \
  }

#define MFMAT(SA, SB)                                                          \
  {                                                                            \
    _Pragma("unroll") for (int nf = 0; nf < 4; ++nf)                           \
        _Pragma("unroll") for (int mf = 0; mf < 4; ++mf)                       \
            acc[mf][nf] = __builtin_amdgcn_mfma_f32_32x32x16_bf16(             \
                SA[mf], SB[nf], acc[mf][nf], 0, 0, 0);                         \
  }

#define SBAR __builtin_amdgcn_sched_barrier(0)
#define LGKM0 asm volatile("s_waitcnt lgkmcnt(0)" ::: "memory")
#define VMC(n) asm volatile("s_waitcnt vmcnt(" #n ")" ::: "memory")
#define BAR __builtin_amdgcn_s_barrier()

  // entry: R0 holds tap0(C); exit: R1 holds tap0(C+1)
#define CBODY(R0A, R0B, R1A, R1B, C, XB)                                       \
  {                                                                            \
    DSRD(R1A, R1B, 1, XB); SBAR; MFMAT(R0A, R0B); /* tap0 */                   \
    DSRD(R0A, R0B, 2, XB); SBAR; MFMAT(R1A, R1B); /* tap1 */                   \
    DSRD(R1A, R1B, 3, XB); SBAR; MFMAT(R0A, R0B); /* tap2 */                   \
    LGKM0; SBAR;                                                               \
    BAR; /* barrier1: L(C) free */                                             \
    GLLL((C) + 1); GLLX((C) + 1, (XB) ^ 1);                                    \
    VMC(12); SBAR; /* H(C) landed */                                           \
    DSRD(R0A, R0B, 4, XB); SBAR; MFMAT(R1A, R1B); /* tap3 */                   \
    DSRD(R1A, R1B, 5, XB); SBAR; MFMAT(R0A, R0B); /* tap4 */                   \
    DSRD(R0A, R0B, 6, XB); SBAR; MFMAT(R1A, R1B); /* tap5 */                   \
    DSRD(R1A, R1B, 7, XB); SBAR; MFMAT(R0A, R0B); /* tap6 */                   \
    DSRD(R0A, R0B, 8, XB); SBAR; MFMAT(R1A, R1B); /* tap7 */                   \
    LGKM0; SBAR;                                                               \
    BAR; /* barrier2: H(C) free */                                             \
    GLLH((C) + 1);                                                             \
    VMC(10); SBAR; /* L(C+1)+x(C+1) landed */                                  \
    DSRD(R1A, R1B, 0, (XB) ^ 1); SBAR; MFMAT(R0A, R0B); /* tap8 */             \
  }

#define CTAIL(R0A, R0B, R1A, R1B, XB)                                          \
  {                                                                            \
    DSRD(R1A, R1B, 1, XB); SBAR; MFMAT(R0A, R0B);                              \
    DSRD(R0A, R0B, 2, XB); SBAR; MFMAT(R1A, R1B);                              \
    DSRD(R1A, R1B, 3, XB); SBAR; MFMAT(R0A, R0B);                              \
    DSRD(R0A, R0B, 4, XB); SBAR; MFMAT(R1A, R1B);                              \
    DSRD(R1A, R1B, 5, XB); SBAR; MFMAT(R0A, R0B);                              \
    DSRD(R0A, R0B, 6, XB); SBAR; MFMAT(R1A, R1B);                              \
    DSRD(R1A, R1B, 7, XB); SBAR; MFMAT(R0A, R0B);                              \
    DSRD(R0A, R0B, 8, XB); SBAR; MFMAT(R1A, R1B);                              \
    MFMAT(R0A, R0B);                                                           \
  }

  // prologue: stage c=0 (A all 18 rounds + x 4 rounds into buf0)
  GLLL(0); GLLH(0); GLLX(0, 0);
  VMC(0);
  BAR;
  SBAR;
  DSRD(PA, PB, 0, 0);
  SBAR;

  for (int cc = 0; cc < 16; cc += 2) {
    CBODY(PA, PB, QA, QB, cc, 0);
    if (cc < 14) {
      CBODY(QA, QB, PA, PB, cc + 1, 1);
    } else {
      CTAIL(QA, QB, PA, PB, 1);
    }
  }

  // ---- fused epilogue: RMSNorm over channels + gamma*16 + SiLU ----
  // D frag: col(px) = lane&31, o-row = (q&3) + 8*(q>>2) + 4*(lane>>5)
#pragma unroll
  for (int r = 0; r < 2; ++r)
#pragma unroll
    for (int h = 0; h < 2; ++h) {
      int nf = r * 2 + h;
      float ps = 0.f;
#pragma unroll
      for (int mf = 0; mf < 4; ++mf)
#pragma unroll
        for (int q = 0; q < 16; ++q) {
          float v = acc[mf][nf][q];
          ps = fmaf(v, v, ps);
        }
      int px = (2 * pq + r) * 64 + h * 32 + l31;
      redl[(oh * 2 + l5) * 256 + px] = ps;
    }
  __syncthreads();
  {
    float ssum = redl[t] + redl[256 + t] + redl[512 + t] + redl[768 + t];
    invs[t] = 16.0f / fmaxf(sqrtf(ssum), 1e-12f);
  }
  __syncthreads();
  float iv4[4];
#pragma unroll
  for (int r = 0; r < 2; ++r)
#pragma unroll
    for (int h = 0; h < 2; ++h)
      iv4[r * 2 + h] = invs[(2 * pq + r) * 64 + h * 32 + l31];

#pragma unroll
  for (int mf = 0; mf < 4; ++mf)
#pragma unroll
    for (int q = 0; q < 16; ++q) {
      int o = oh * 128 + mf * 32 + (q & 3) + 8 * (q >> 2) + 4 * l5;
      float g = gsm[o];
      size_t ob = (((size_t)b * 256 + o) * 64);
#pragma unroll
      for (int r = 0; r < 2; ++r)
#pragma unroll
        for (int h = 0; h < 2; ++h) {
          float v = acc[mf][r * 2 + h][q] * iv4[r * 2 + h] * g;
          float sg = 1.0f / (1.0f + expf(-v));
          out[(ob + (r0 + 2 * pq + r)) * 64 + h * 32 + l31] = v * sg;
        }
    }
#undef GLLL
#undef GLLH
#undef GLLX
#undef DSRD
#undef MFMAT
#undef SBAR
#undef LGKM0
#undef VMC
#undef BAR
#undef CBODY
#undef CTAIL
}

extern "C" void kernel_launch(void* const* d_in, const int* in_sizes, int n_in,
                              void* d_out, int out_size, void* d_ws, size_t ws_size,
                              hipStream_t stream) {
  const float* x = (const float*)d_in[0];
  const float* mod = (const float*)d_in[1];
  const float* kmod = (const float*)d_in[2];
  const float* weights = (const float*)d_in[3];
  const float* gamma = (const float*)d_in[4];
  float* out = (float*)d_out;

  // ws layout: xq FIRST (35,684,352 B) so conv's uniform 4-round x-stage may
  // overrun harmlessly into wq; wq (18,874,368 B) after. Total ~54.6 MB.
  unsigned short* xq = (unsigned short*)d_ws;
  unsigned short* wq = (unsigned short*)((char*)d_ws + 35684352);

  wprep<<<512, 256, 0, stream>>>(mod, kmod, weights, wq);
  xprep<<<16 * 16 * 66, 256, 0, stream>>>(x, xq);
  conv_fused<<<256, 256, 0, stream>>>(xq, wq, gamma, out);
}

// Round 13
// 124.235 us; speedup vs baseline: 2.1673x; 2.1673x over previous
//
#include <hip/hip_runtime.h>
#include <math.h>

// B=16, C_IN=256, C_OUT=256, H=W=64, K=3, NK=2
// weights: [2][256][256][3][3]; bank stride 589824 floats; per-o stride 2304.
//
// Pipeline (3 kernels):
//  1. wprep: combined+modulated+demod bf16 weights -> wq, 32x32-MFMA LDS image
//     per (b,c16): [tap9][oh2][mf4][lane64][e8] (36864 ush = 73728 B), where
//     A-frag: o = oh*128 + mf*32 + (lane&31), i = c*16 + (lane>>5)*8 + e.
//  2. xprep: x -> bf16 xq [b][c16][rowp66][colp66][i16], halo zeros, plain
//     layout (32x32 B-reads conflict-light without swizzle).
//  3. conv_fused: implicit GEMM via mfma_f32_32x32x16_bf16 (K=16 = 2 i-octets
//     per tap; 9 taps = 9 MFMAs, no dummy). Block 256 thr (4 waves) =
//     256 o x 4 rows x 64 px; wave = (oh,pq) tile 128o x 128px, mf4 x nf4,
//     acc 256 f32 (AGPR). Fragments read INLINE per tap (no P/Q dbuf -> no
//     spill; R10 proved acc256+inline fits at 184 VGPR). A single-buffered in
//     2 rolling halves (taps0-3 / taps4-8), x double-buffered, symmetric
//     counted vmcnt(12) gates. Epilogue: fused RMSNorm * gamma * 16 + SiLU.

typedef __attribute__((ext_vector_type(8))) short short8;
typedef __attribute__((ext_vector_type(16))) float f32x16;

#define GLL16(src, dst)                                                       \
  __builtin_amdgcn_global_load_lds(                                           \
      (const __attribute__((address_space(1))) unsigned int*)(src),           \
      (__attribute__((address_space(3))) unsigned int*)(dst), 16, 0, 0)

static __device__ __forceinline__ unsigned short f2bf(float v) {
  union { float f; unsigned u; } u;
  u.f = v;
  unsigned r = u.u + 0x7FFF + ((u.u >> 16) & 1);  // RNE
  return (unsigned short)(r >> 16);
}

// ---------------------------------------------------------------------------
// Kernel 1: fused weight prep. Grid 512 = b(16) x oq(32 o-octets), 256 thr.
// ---------------------------------------------------------------------------
__global__ __launch_bounds__(256) void wprep(
    const float* __restrict__ mod, const float* __restrict__ kmod,
    const float* __restrict__ weights, unsigned short* __restrict__ wq) {
  int blk = blockIdx.x;  // b*32 + oq
  int b = blk >> 5, oq = blk & 31;
  int t = threadIdx.x;
  int o_l = t >> 5, its = t & 31;
  int o = oq * 8 + o_l;

  float k0 = kmod[b * 2 + 0], k1 = kmod[b * 2 + 1];
  float mx = fmaxf(k0, k1);
  float e0 = expf(k0 - mx), e1 = expf(k1 - mx);
  float ai = 1.0f / (e0 + e1);
  float a0 = e0 * ai, a1 = e1 * ai;

  float wv[9][8];  // [j][e]
  float s = 0.0f;
  const float* w0 = &weights[((size_t)o * 256 + its * 8) * 9];
  const float* w1 = w0 + 589824;
#pragma unroll
  for (int e = 0; e < 8; ++e) {
    float f = mod[b * 256 + its * 8 + e] + 1.0f;
#pragma unroll
    for (int j = 0; j < 9; ++j) {
      float v = (a0 * w0[e * 9 + j] + a1 * w1[e * 9 + j]) * f;
      wv[j][e] = v;
      s = fmaf(v, v, s);
    }
  }

  __shared__ float red[8][32];
  __shared__ float scl[8];
  red[o_l][its] = s;
  __syncthreads();
  if (t < 8) {
    float tot = 0.0f;
#pragma unroll
    for (int k = 0; k < 32; ++k) tot += red[t][k];
    scl[t] = rsqrtf(fmaxf(tot, 1e-8f));
  }
  __syncthreads();
  float sc = scl[o_l];

  int c = its >> 1, io = its & 1;
  int oh = o >> 7, mf = (o >> 5) & 3;
  int lane2 = (o & 31) + io * 32;
  // chunk [tap9][oh2][mf4][lane64][e8] ush per (b,c)
  size_t cbase = ((size_t)(b * 16 + c)) * 36864 + oh * 2048 + mf * 512 + lane2 * 8;
#pragma unroll
  for (int j = 0; j < 9; ++j) {
    short8 pk;
#pragma unroll
    for (int e = 0; e < 8; ++e) pk[e] = (short)f2bf(wv[j][e] * sc);
    *(short8*)(wq + cbase + j * 4096) = pk;
  }
}

// ---------------------------------------------------------------------------
// Kernel 2: x prep -> bf16 xq [b][c][rowp66][colp66][i16], halo zeroed, plain.
// ---------------------------------------------------------------------------
__global__ __launch_bounds__(256) void xprep(
    const float* __restrict__ x, unsigned short* __restrict__ xq) {
  int blk = blockIdx.x;  // (b*16 + c)*66 + rowp
  int rowp = blk % 66;
  int bc = blk / 66;
  int b = bc >> 4, c = bc & 15;
  int t = threadIdx.x;
  size_t obase = (size_t)blk * 1056;

  if (rowp == 0 || rowp == 65) {
    for (int idx = t; idx < 1056; idx += 256) xq[obase + idx] = 0;
    return;
  }
  __shared__ __align__(16) unsigned short xs2[1056];
  int row = rowp - 1;
  for (int idx = t; idx < 1056; idx += 256) xs2[idx] = 0;
  __syncthreads();
#pragma unroll
  for (int k = 0; k < 4; ++k) {
    int idx = t + k * 256;  // 0..1023
    int il = idx >> 6, col = idx & 63;
    float v = x[(((size_t)b * 256 + c * 16 + il) * 64 + row) * 64 + col];
    xs2[(col + 1) * 16 + il] = f2bf(v);
  }
  __syncthreads();
  if (t < 132) *(short8*)(xq + obase + (size_t)t * 8) = *(const short8*)&xs2[t * 8];
}

// ---------------------------------------------------------------------------
// Kernel 3: fused conv + RMSNorm + SiLU. Grid 256 (XCD-clustered), 256 thr.
// ---------------------------------------------------------------------------
__global__ __launch_bounds__(256, 1) void conv_fused(
    const unsigned short* __restrict__ xq, const unsigned short* __restrict__ wq,
    const float* __restrict__ gamma, float* __restrict__ out) {
  __shared__ __align__(16) unsigned short wsm[36864];    // [tap][oh][mf][lane][e]
  __shared__ __align__(16) unsigned short xsm[2][8192];  // 16384 B each
  __shared__ float redl[1024];                           // [adder4][px256]
  __shared__ float invs[256];
  __shared__ float gsm[256];

  int bid = blockIdx.x;
  int xcd = bid & 7;
  int kk = bid >> 3;            // 0..31
  int b = xcd * 2 + (kk >> 4);  // 2 batches per XCD
  int rt = kk & 15;             // 4-row tile
  int r0 = rt * 4;

  int t = threadIdx.x;
  int w = t >> 6, lane = t & 63;
  int oh = w >> 1, pq = w & 1;
  int l31 = lane & 31, l5 = lane >> 5;

  gsm[t] = gamma[t];

  // A base: + imm(tap*8192 + mf*1024) at use
  const char* aw = (const char*)wsm + oh * 4096 + lane * 16;
  // B bases per x-buffer: + imm(kh*2112 + kw*32 + r*2112 + h*1024) at use
  const char* xb0 = (const char*)xsm[0] + ((2 * pq) * 66 + l31) * 32 + l5 * 16;
  const char* xb1 = (const char*)xsm[1] + ((2 * pq) * 66 + l31) * 32 + l5 * 16;

  f32x16 acc[4][4];
#pragma unroll
  for (int mf = 0; mf < 4; ++mf)
#pragma unroll
    for (int nf = 0; nf < 4; ++nf)
#pragma unroll
      for (int q = 0; q < 16; ++q) acc[mf][nf][q] = 0.f;

  // ---- staging macros ----
#define GLLL(cn)                                                               \
  _Pragma("unroll") for (int r = 0; r < 8; ++r) {                              \
    GLL16(wq + ((size_t)(b * 16 + (cn))) * 36864 + (r * 256 + t) * 8,          \
          &wsm[(r * 256 + t) * 8]);                                            \
  }
#define GLLH(cn)                                                               \
  _Pragma("unroll") for (int r = 0; r < 10; ++r) {                             \
    GLL16(wq + ((size_t)(b * 16 + (cn))) * 36864 + 16384 + (r * 256 + t) * 8,  \
          &wsm[16384 + (r * 256 + t) * 8]);                                    \
  }
#define GLLX(cn, nb)                                                           \
  _Pragma("unroll") for (int r = 0; r < 4; ++r) {                              \
    GLL16(xq + ((size_t)((b * 16 + (cn)) * 66 + r0)) * 1056 + (r * 256 + t) * 8, \
          &xsm[nb][(r * 256 + t) * 8]);                                        \
  }

  // inline frag read + 16 MFMAs for one tap
#define TAP(T, xbp)                                                            \
  {                                                                            \
    short8 A[4], Bv[4];                                                        \
    _Pragma("unroll") for (int mf = 0; mf < 4; ++mf)                           \
        A[mf] = *(const short8*)(aw + (T) * 8192 + mf * 1024);                 \
    _Pragma("unroll") for (int r = 0; r < 2; ++r)                              \
        _Pragma("unroll") for (int h = 0; h < 2; ++h)                          \
            Bv[r * 2 + h] = *(const short8*)((xbp) + ((T) / 3) * 2112 +        \
                                             ((T) % 3) * 32 + r * 2112 +       \
                                             h * 1024);                        \
    _Pragma("unroll") for (int nf = 0; nf < 4; ++nf)                           \
        _Pragma("unroll") for (int mf = 0; mf < 4; ++mf)                       \
            acc[mf][nf] = __builtin_amdgcn_mfma_f32_32x32x16_bf16(             \
                A[mf], Bv[nf], acc[mf][nf], 0, 0, 0);                          \
  }

#define SBAR __builtin_amdgcn_sched_barrier(0)
#define LGKM0 asm volatile("s_waitcnt lgkmcnt(0)" ::: "memory")
#define VMC(n) asm volatile("s_waitcnt vmcnt(" #n ")" ::: "memory")
#define BAR __builtin_amdgcn_s_barrier()

  // prologue: stage c=0 fully (22 GLL rounds)
  GLLL(0); GLLH(0); GLLX(0, 0);
  VMC(0);
  BAR;
  SBAR;

  for (int c = 0; c < 16; ++c) {
    const char* xbp = (c & 1) ? xb1 : xb0;
    // ---- taps 0-3 from L half + x(c) ----
    TAP(0, xbp); TAP(1, xbp); TAP(2, xbp); TAP(3, xbp);
    LGKM0; SBAR;
    BAR;  // L(c) + nothing else pending: L free for overwrite
    if (c < 15) {
      GLLL(c + 1); GLLX(c + 1, (c & 1) ^ 1);
      VMC(12); SBAR;  // H(c) (10 rounds, issued last iter) landed
    }
    // ---- taps 4-8 from H half ----
    TAP(4, xbp); TAP(5, xbp); TAP(6, xbp); TAP(7, xbp); TAP(8, xbp);
    LGKM0; SBAR;
    BAR;  // H(c) free for overwrite
    if (c < 15) {
      GLLH(c + 1);
      VMC(10); SBAR;  // L(c+1) + x(c+1) (12 rounds) landed; H(c+1) in flight
    }
  }

  // ---- fused epilogue: RMSNorm over channels + gamma*16 + SiLU ----
  // D frag: col(px) = lane&31, o-row = (q&3) + 8*(q>>2) + 4*(lane>>5)
#pragma unroll
  for (int r = 0; r < 2; ++r)
#pragma unroll
    for (int h = 0; h < 2; ++h) {
      int nf = r * 2 + h;
      float ps = 0.f;
#pragma unroll
      for (int mf = 0; mf < 4; ++mf)
#pragma unroll
        for (int q = 0; q < 16; ++q) {
          float v = acc[mf][nf][q];
          ps = fmaf(v, v, ps);
        }
      int px = (2 * pq + r) * 64 + h * 32 + l31;
      redl[(oh * 2 + l5) * 256 + px] = ps;
    }
  __syncthreads();
  {
    float ssum = redl[t] + redl[256 + t] + redl[512 + t] + redl[768 + t];
    invs[t] = 16.0f / fmaxf(sqrtf(ssum), 1e-12f);
  }
  __syncthreads();
  float iv4[4];
#pragma unroll
  for (int r = 0; r < 2; ++r)
#pragma unroll
    for (int h = 0; h < 2; ++h)
      iv4[r * 2 + h] = invs[(2 * pq + r) * 64 + h * 32 + l31];

#pragma unroll
  for (int mf = 0; mf < 4; ++mf)
#pragma unroll
    for (int q = 0; q < 16; ++q) {
      int o = oh * 128 + mf * 32 + (q & 3) + 8 * (q >> 2) + 4 * l5;
      float g = gsm[o];
      size_t ob = (((size_t)b * 256 + o) * 64);
#pragma unroll
      for (int r = 0; r < 2; ++r)
#pragma unroll
        for (int h = 0; h < 2; ++h) {
          float v = acc[mf][r * 2 + h][q] * iv4[r * 2 + h] * g;
          float sg = 1.0f / (1.0f + expf(-v));
          out[(ob + (r0 + 2 * pq + r)) * 64 + h * 32 + l31] = v * sg;
        }
    }
#undef GLLL
#undef GLLH
#undef GLLX
#undef TAP
#undef SBAR
#undef LGKM0
#undef VMC
#undef BAR
}

extern "C" void kernel_launch(void* const* d_in, const int* in_sizes, int n_in,
                              void* d_out, int out_size, void* d_ws, size_t ws_size,
                              hipStream_t stream) {
  const float* x = (const float*)d_in[0];
  const float* mod = (const float*)d_in[1];
  const float* kmod = (const float*)d_in[2];
  const float* weights = (const float*)d_in[3];
  const float* gamma = (const float*)d_in[4];
  float* out = (float*)d_out;

  // ws layout: xq FIRST (35,684,352 B) so conv's uniform 4-round x-stage may
  // overrun harmlessly into wq; wq (18,874,368 B) after. Total ~54.6 MB.
  unsigned short* xq = (unsigned short*)d_ws;
  unsigned short* wq = (unsigned short*)((char*)d_ws + 35684352);

  wprep<<<512, 256, 0, stream>>>(mod, kmod, weights, wq);
  xprep<<<16 * 16 * 66, 256, 0, stream>>>(x, xq);
  conv_fused<<<256, 256, 0, stream>>>(xq, wq, gamma, out);
}

// Round 14
// 121.207 us; speedup vs baseline: 2.2215x; 1.0250x over previous
//
#include <hip/hip_runtime.h>
#include <math.h>

// B=16, C_IN=256, C_OUT=256, H=W=64, K=3, NK=2
// weights: [2][256][256][3][3]; bank stride 589824 floats; per-o stride 2304.
//
// Pipeline (3 kernels):
//  1. wprep: combined+modulated+demod bf16 weights -> wq, 32x32-MFMA LDS image
//     per (b,c16): [tap9][oh2][mf4][lane64][e8] (36864 ush = 73728 B), where
//     A-frag: o = oh*128 + mf*32 + (lane&31), i = c*16 + (lane>>5)*8 + e.
//  2. xprep: x -> bf16 xq [b][c16][rowp66][colp66][i16], halo zeros, plain.
//  3. conv_fused: implicit GEMM via mfma_f32_32x32x16_bf16 (9 taps = 9 MFMAs).
//     Block 512 thr (8 waves, 2/SIMD) = 256 o x 4 rows x 64 px; wave =
//     (oh,ps) tile 128o x 64px, mf4 x nf2, acc 128 f32. Two waves per SIMD
//     interleave inside tap regions (m114 latency hiding). A staged in 2
//     rolling halves (taps0-3 / taps4-8), x double-buffered. Race-free gating:
//     vmcnt(0) drain BEFORE each barrier (loads were issued a half-step
//     earlier -> drain is free), so cross-wave LDS visibility is rigorous.
//     Epilogue: fused channel RMSNorm * gamma * 16 + SiLU.

typedef __attribute__((ext_vector_type(8))) short short8;
typedef __attribute__((ext_vector_type(16))) float f32x16;

#define GLL16(src, dst)                                                       \
  __builtin_amdgcn_global_load_lds(                                           \
      (const __attribute__((address_space(1))) unsigned int*)(src),           \
      (__attribute__((address_space(3))) unsigned int*)(dst), 16, 0, 0)

static __device__ __forceinline__ unsigned short f2bf(float v) {
  union { float f; unsigned u; } u;
  u.f = v;
  unsigned r = u.u + 0x7FFF + ((u.u >> 16) & 1);  // RNE
  return (unsigned short)(r >> 16);
}

// ---------------------------------------------------------------------------
// Kernel 1: fused weight prep. Grid 512 = b(16) x oq(32 o-octets), 256 thr.
// ---------------------------------------------------------------------------
__global__ __launch_bounds__(256) void wprep(
    const float* __restrict__ mod, const float* __restrict__ kmod,
    const float* __restrict__ weights, unsigned short* __restrict__ wq) {
  int blk = blockIdx.x;  // b*32 + oq
  int b = blk >> 5, oq = blk & 31;
  int t = threadIdx.x;
  int o_l = t >> 5, its = t & 31;
  int o = oq * 8 + o_l;

  float k0 = kmod[b * 2 + 0], k1 = kmod[b * 2 + 1];
  float mx = fmaxf(k0, k1);
  float e0 = expf(k0 - mx), e1 = expf(k1 - mx);
  float ai = 1.0f / (e0 + e1);
  float a0 = e0 * ai, a1 = e1 * ai;

  float wv[9][8];  // [j][e]
  float s = 0.0f;
  const float* w0 = &weights[((size_t)o * 256 + its * 8) * 9];
  const float* w1 = w0 + 589824;
#pragma unroll
  for (int e = 0; e < 8; ++e) {
    float f = mod[b * 256 + its * 8 + e] + 1.0f;
#pragma unroll
    for (int j = 0; j < 9; ++j) {
      float v = (a0 * w0[e * 9 + j] + a1 * w1[e * 9 + j]) * f;
      wv[j][e] = v;
      s = fmaf(v, v, s);
    }
  }

  __shared__ float red[8][32];
  __shared__ float scl[8];
  red[o_l][its] = s;
  __syncthreads();
  if (t < 8) {
    float tot = 0.0f;
#pragma unroll
    for (int k = 0; k < 32; ++k) tot += red[t][k];
    scl[t] = rsqrtf(fmaxf(tot, 1e-8f));
  }
  __syncthreads();
  float sc = scl[o_l];

  int c = its >> 1, io = its & 1;
  int oh = o >> 7, mf = (o >> 5) & 3;
  int lane2 = (o & 31) + io * 32;
  // chunk [tap9][oh2][mf4][lane64][e8] ush per (b,c)
  size_t cbase = ((size_t)(b * 16 + c)) * 36864 + oh * 2048 + mf * 512 + lane2 * 8;
#pragma unroll
  for (int j = 0; j < 9; ++j) {
    short8 pk;
#pragma unroll
    for (int e = 0; e < 8; ++e) pk[e] = (short)f2bf(wv[j][e] * sc);
    *(short8*)(wq + cbase + j * 4096) = pk;
  }
}

// ---------------------------------------------------------------------------
// Kernel 2: x prep -> bf16 xq [b][c][rowp66][colp66][i16], halo zeroed, plain.
// ---------------------------------------------------------------------------
__global__ __launch_bounds__(256) void xprep(
    const float* __restrict__ x, unsigned short* __restrict__ xq) {
  int blk = blockIdx.x;  // (b*16 + c)*66 + rowp
  int rowp = blk % 66;
  int bc = blk / 66;
  int b = bc >> 4, c = bc & 15;
  int t = threadIdx.x;
  size_t obase = (size_t)blk * 1056;

  if (rowp == 0 || rowp == 65) {
    for (int idx = t; idx < 1056; idx += 256) xq[obase + idx] = 0;
    return;
  }
  __shared__ __align__(16) unsigned short xs2[1056];
  int row = rowp - 1;
  for (int idx = t; idx < 1056; idx += 256) xs2[idx] = 0;
  __syncthreads();
#pragma unroll
  for (int k = 0; k < 4; ++k) {
    int idx = t + k * 256;  // 0..1023
    int il = idx >> 6, col = idx & 63;
    float v = x[(((size_t)b * 256 + c * 16 + il) * 64 + row) * 64 + col];
    xs2[(col + 1) * 16 + il] = f2bf(v);
  }
  __syncthreads();
  if (t < 132) *(short8*)(xq + obase + (size_t)t * 8) = *(const short8*)&xs2[t * 8];
}

// ---------------------------------------------------------------------------
// Kernel 3: fused conv + RMSNorm + SiLU. Grid 256 (XCD-clustered), 512 thr.
// ---------------------------------------------------------------------------
__global__ __launch_bounds__(512, 2) void conv_fused(
    const unsigned short* __restrict__ xq, const unsigned short* __restrict__ wq,
    const float* __restrict__ gamma, float* __restrict__ out) {
  __shared__ __align__(16) unsigned short wsm[36864];    // [tap][oh][mf][lane][e]
  __shared__ __align__(16) unsigned short xsm[2][8192];  // 16384 B each
  __shared__ float redl[1024];                           // [adder4][px256]
  __shared__ float invs[256];
  __shared__ float gsm[256];

  int bid = blockIdx.x;
  int xcd = bid & 7;
  int kk = bid >> 3;            // 0..31
  int b = xcd * 2 + (kk >> 4);  // 2 batches per XCD
  int rt = kk & 15;             // 4-row tile
  int r0 = rt * 4;

  int t = threadIdx.x;
  int w = t >> 6, lane = t & 63;
  int oh = w & 1, ps = w >> 1;  // wave = (oh: 128-o half, ps: row slot 0..3)
  int l31 = lane & 31, l5 = lane >> 5;

  if (t < 256) gsm[t] = gamma[t];

  // A base: + imm(tap*8192 + mf*1024) at use
  const char* aw = (const char*)wsm + oh * 4096 + lane * 16;
  // B bases per x-buffer: + imm(kh*2112 + kw*32 + h*1024) at use
  const char* xb0 = (const char*)xsm[0] + (ps * 66 + l31) * 32 + l5 * 16;
  const char* xb1 = (const char*)xsm[1] + (ps * 66 + l31) * 32 + l5 * 16;

  f32x16 acc[4][2];
#pragma unroll
  for (int mf = 0; mf < 4; ++mf)
#pragma unroll
    for (int h = 0; h < 2; ++h)
#pragma unroll
      for (int q = 0; q < 16; ++q) acc[mf][h][q] = 0.f;

  // ---- staging macros (512 thr, 8192 B per round) ----
#define GLLL(cn)                                                               \
  _Pragma("unroll") for (int r = 0; r < 4; ++r) {                              \
    GLL16(wq + ((size_t)(b * 16 + (cn))) * 36864 + (r * 512 + t) * 8,          \
          &wsm[(r * 512 + t) * 8]);                                            \
  }
#define GLLH(cn)                                                               \
  _Pragma("unroll") for (int r = 0; r < 5; ++r) {                              \
    GLL16(wq + ((size_t)(b * 16 + (cn))) * 36864 + 16384 + (r * 512 + t) * 8,  \
          &wsm[16384 + (r * 512 + t) * 8]);                                    \
  }
#define GLLX(cn, nb)                                                           \
  _Pragma("unroll") for (int r = 0; r < 2; ++r) {                              \
    GLL16(xq + ((size_t)((b * 16 + (cn)) * 66 + r0)) * 1056 + (r * 512 + t) * 8, \
          &xsm[nb][(r * 512 + t) * 8]);                                        \
  }

  // inline frag read + 8 MFMAs for one tap
#define TAP(T, xbp)                                                            \
  {                                                                            \
    short8 A[4], Bv[2];                                                        \
    _Pragma("unroll") for (int mf = 0; mf < 4; ++mf)                           \
        A[mf] = *(const short8*)(aw + (T) * 8192 + mf * 1024);                 \
    _Pragma("unroll") for (int h = 0; h < 2; ++h)                              \
        Bv[h] = *(const short8*)((xbp) + ((T) / 3) * 2112 + ((T) % 3) * 32 +   \
                                 h * 1024);                                    \
    _Pragma("unroll") for (int h = 0; h < 2; ++h)                              \
        _Pragma("unroll") for (int mf = 0; mf < 4; ++mf)                       \
            acc[mf][h] = __builtin_amdgcn_mfma_f32_32x32x16_bf16(              \
                A[mf], Bv[h], acc[mf][h], 0, 0, 0);                            \
  }

#define SBAR __builtin_amdgcn_sched_barrier(0)
#define LGKM0 asm volatile("s_waitcnt lgkmcnt(0)" ::: "memory")
#define VM0 asm volatile("s_waitcnt vmcnt(0)" ::: "memory")
#define BAR __builtin_amdgcn_s_barrier()

  // prologue: stage c=0 fully (11 GLL rounds)
  GLLL(0); GLLH(0); GLLX(0, 0);
  VM0;
  BAR;
  SBAR;

  for (int c = 0; c < 16; ++c) {
    const char* xbp = (c & 1) ? xb1 : xb0;
    // ---- taps 0-3 from L half + x(c) ----
    TAP(0, xbp); TAP(1, xbp); TAP(2, xbp); TAP(3, xbp);
    LGKM0;  // my L/x reads done
    VM0;    // H(c) rounds (issued last half-step) drained -> visible after BAR
    SBAR;
    BAR;
    SBAR;
    if (c < 15) { GLLL(c + 1); GLLX(c + 1, (c & 1) ^ 1); }  // in flight over taps4-8
    // ---- taps 4-8 from H half ----
    TAP(4, xbp); TAP(5, xbp); TAP(6, xbp); TAP(7, xbp); TAP(8, xbp);
    LGKM0;  // my H reads done
    VM0;    // L(c+1)+x(c+1) drained -> visible after BAR
    SBAR;
    BAR;
    SBAR;
    if (c < 15) { GLLH(c + 1); }  // in flight over taps0-3 of c+1
  }

  // ---- fused epilogue: RMSNorm over channels + gamma*16 + SiLU ----
  // D frag: col(px) = lane&31, o-row = (q&3) + 8*(q>>2) + 4*(lane>>5)
#pragma unroll
  for (int h = 0; h < 2; ++h) {
    float pssum = 0.f;
#pragma unroll
    for (int mf = 0; mf < 4; ++mf)
#pragma unroll
      for (int q = 0; q < 16; ++q) {
        float v = acc[mf][h][q];
        pssum = fmaf(v, v, pssum);
      }
    int px = ps * 64 + h * 32 + l31;
    redl[(oh * 2 + l5) * 256 + px] = pssum;
  }
  __syncthreads();
  if (t < 256) {
    float ssum = redl[t] + redl[256 + t] + redl[512 + t] + redl[768 + t];
    invs[t] = 16.0f / fmaxf(sqrtf(ssum), 1e-12f);
  }
  __syncthreads();
  float iv2[2];
#pragma unroll
  for (int h = 0; h < 2; ++h) iv2[h] = invs[ps * 64 + h * 32 + l31];

#pragma unroll
  for (int mf = 0; mf < 4; ++mf)
#pragma unroll
    for (int q = 0; q < 16; ++q) {
      int o = oh * 128 + mf * 32 + (q & 3) + 8 * (q >> 2) + 4 * l5;
      float g = gsm[o];
      size_t ob = ((size_t)b * 256 + o) * 64 + (r0 + ps);
#pragma unroll
      for (int h = 0; h < 2; ++h) {
        float v = acc[mf][h][q] * iv2[h] * g;
        float sg = 1.0f / (1.0f + expf(-v));
        out[ob * 64 + h * 32 + l31] = v * sg;
      }
    }
#undef GLLL
#undef GLLH
#undef GLLX
#undef TAP
#undef SBAR
#undef LGKM0
#undef VM0
#undef BAR
}

extern "C" void kernel_launch(void* const* d_in, const int* in_sizes, int n_in,
                              void* d_out, int out_size, void* d_ws, size_t ws_size,
                              hipStream_t stream) {
  const float* x = (const float*)d_in[0];
  const float* mod = (const float*)d_in[1];
  const float* kmod = (const float*)d_in[2];
  const float* weights = (const float*)d_in[3];
  const float* gamma = (const float*)d_in[4];
  float* out = (float*)d_out;

  // ws layout: xq FIRST (35,684,352 B) so conv's uniform x-stage rounds may
  // overrun harmlessly into wq; wq (18,874,368 B) after. Total ~54.6 MB.
  unsigned short* xq = (unsigned short*)d_ws;
  unsigned short* wq = (unsigned short*)((char*)d_ws + 35684352);

  wprep<<<512, 256, 0, stream>>>(mod, kmod, weights, wq);
  xprep<<<16 * 16 * 66, 256, 0, stream>>>(x, xq);
  conv_fused<<<256, 512, 0, stream>>>(xq, wq, gamma, out);
}

// Round 15
// 120.891 us; speedup vs baseline: 2.2273x; 1.0026x over previous
//
#include <hip/hip_runtime.h>
#include <math.h>

// B=16, C_IN=256, C_OUT=256, H=W=64, K=3, NK=2
// weights: [2][256][256][3][3]; bank stride 589824 floats; per-o stride 2304.
//
// Pipeline (3 kernels):
//  1. wprep: combined+modulated+demod bf16 weights -> wq, 32x32-MFMA LDS image
//     per (b,c16): [tap9][oh2][mf4][lane64][e8] (36864 ush = 73728 B), where
//     A-frag: o = oh*128 + mf*32 + (lane&31), i = c*16 + (lane>>5)*8 + e.
//  2. xprep: x -> bf16 xq [b][c16][rowp66][colp66][i16], halo zeros, plain.
//  3. conv_fused: implicit GEMM via mfma_f32_32x32x16_bf16 (9 taps = 9 MFMAs).
//     Block 512 thr (8 waves, 2/SIMD) = 256 o x 4 rows x 64 px; wave =
//     (oh,ps) tile 128o x 64px, mf4 x nf2, acc 128 f32. Two waves per SIMD
//     interleave inside tap regions (m114 latency hiding). A staged in 2
//     rolling halves (taps0-3 / taps4-8), x double-buffered. Race-free gating:
//     vmcnt(0) drain BEFORE each barrier (loads were issued a half-step
//     earlier -> drain is free), so cross-wave LDS visibility is rigorous.
//     Epilogue: fused channel RMSNorm * gamma * 16 + SiLU.

typedef __attribute__((ext_vector_type(8))) short short8;
typedef __attribute__((ext_vector_type(16))) float f32x16;

#define GLL16(src, dst)                                                       \
  __builtin_amdgcn_global_load_lds(                                           \
      (const __attribute__((address_space(1))) unsigned int*)(src),           \
      (__attribute__((address_space(3))) unsigned int*)(dst), 16, 0, 0)

static __device__ __forceinline__ unsigned short f2bf(float v) {
  union { float f; unsigned u; } u;
  u.f = v;
  unsigned r = u.u + 0x7FFF + ((u.u >> 16) & 1);  // RNE
  return (unsigned short)(r >> 16);
}

// ---------------------------------------------------------------------------
// Kernel 1: fused weight prep. Grid 512 = b(16) x oq(32 o-octets), 256 thr.
// ---------------------------------------------------------------------------
__global__ __launch_bounds__(256) void wprep(
    const float* __restrict__ mod, const float* __restrict__ kmod,
    const float* __restrict__ weights, unsigned short* __restrict__ wq) {
  int blk = blockIdx.x;  // b*32 + oq
  int b = blk >> 5, oq = blk & 31;
  int t = threadIdx.x;
  int o_l = t >> 5, its = t & 31;
  int o = oq * 8 + o_l;

  float k0 = kmod[b * 2 + 0], k1 = kmod[b * 2 + 1];
  float mx = fmaxf(k0, k1);
  float e0 = expf(k0 - mx), e1 = expf(k1 - mx);
  float ai = 1.0f / (e0 + e1);
  float a0 = e0 * ai, a1 = e1 * ai;

  float wv[9][8];  // [j][e]
  float s = 0.0f;
  const float* w0 = &weights[((size_t)o * 256 + its * 8) * 9];
  const float* w1 = w0 + 589824;
#pragma unroll
  for (int e = 0; e < 8; ++e) {
    float f = mod[b * 256 + its * 8 + e] + 1.0f;
#pragma unroll
    for (int j = 0; j < 9; ++j) {
      float v = (a0 * w0[e * 9 + j] + a1 * w1[e * 9 + j]) * f;
      wv[j][e] = v;
      s = fmaf(v, v, s);
    }
  }

  __shared__ float red[8][32];
  __shared__ float scl[8];
  red[o_l][its] = s;
  __syncthreads();
  if (t < 8) {
    float tot = 0.0f;
#pragma unroll
    for (int k = 0; k < 32; ++k) tot += red[t][k];
    scl[t] = rsqrtf(fmaxf(tot, 1e-8f));
  }
  __syncthreads();
  float sc = scl[o_l];

  int c = its >> 1, io = its & 1;
  int oh = o >> 7, mf = (o >> 5) & 3;
  int lane2 = (o & 31) + io * 32;
  // chunk [tap9][oh2][mf4][lane64][e8] ush per (b,c)
  size_t cbase = ((size_t)(b * 16 + c)) * 36864 + oh * 2048 + mf * 512 + lane2 * 8;
#pragma unroll
  for (int j = 0; j < 9; ++j) {
    short8 pk;
#pragma unroll
    for (int e = 0; e < 8; ++e) pk[e] = (short)f2bf(wv[j][e] * sc);
    *(short8*)(wq + cbase + j * 4096) = pk;
  }
}

// ---------------------------------------------------------------------------
// Kernel 2: x prep -> bf16 xq [b][c][rowp66][colp66][i16], halo zeroed, plain.
// ---------------------------------------------------------------------------
__global__ __launch_bounds__(256) void xprep(
    const float* __restrict__ x, unsigned short* __restrict__ xq) {
  int blk = blockIdx.x;  // (b*16 + c)*66 + rowp
  int rowp = blk % 66;
  int bc = blk / 66;
  int b = bc >> 4, c = bc & 15;
  int t = threadIdx.x;
  size_t obase = (size_t)blk * 1056;

  if (rowp == 0 || rowp == 65) {
    for (int idx = t; idx < 1056; idx += 256) xq[obase + idx] = 0;
    return;
  }
  __shared__ __align__(16) unsigned short xs2[1056];
  int row = rowp - 1;
  for (int idx = t; idx < 1056; idx += 256) xs2[idx] = 0;
  __syncthreads();
#pragma unroll
  for (int k = 0; k < 4; ++k) {
    int idx = t + k * 256;  // 0..1023
    int il = idx >> 6, col = idx & 63;
    float v = x[(((size_t)b * 256 + c * 16 + il) * 64 + row) * 64 + col];
    xs2[(col + 1) * 16 + il] = f2bf(v);
  }
  __syncthreads();
  if (t < 132) *(short8*)(xq + obase + (size_t)t * 8) = *(const short8*)&xs2[t * 8];
}

// ---------------------------------------------------------------------------
// Kernel 3: fused conv + RMSNorm + SiLU. Grid 256 (XCD-clustered), 512 thr.
// ---------------------------------------------------------------------------
__global__ __launch_bounds__(512, 2) void conv_fused(
    const unsigned short* __restrict__ xq, const unsigned short* __restrict__ wq,
    const float* __restrict__ gamma, float* __restrict__ out) {
  __shared__ __align__(16) unsigned short wsm[36864];    // [tap][oh][mf][lane][e]
  __shared__ __align__(16) unsigned short xsm[2][8192];  // 16384 B each
  __shared__ float redl[1024];                           // [adder4][px256]
  __shared__ float invs[256];
  __shared__ float gsm[256];

  int bid = blockIdx.x;
  int xcd = bid & 7;
  int kk = bid >> 3;            // 0..31
  int b = xcd * 2 + (kk >> 4);  // 2 batches per XCD
  int rt = kk & 15;             // 4-row tile
  int r0 = rt * 4;

  int t = threadIdx.x;
  int w = t >> 6, lane = t & 63;
  int oh = w & 1, ps = w >> 1;  // wave = (oh: 128-o half, ps: row slot 0..3)
  int l31 = lane & 31, l5 = lane >> 5;

  if (t < 256) gsm[t] = gamma[t];

  // A base: + imm(tap*8192 + mf*1024) at use
  const char* aw = (const char*)wsm + oh * 4096 + lane * 16;
  // B bases per x-buffer: + imm(kh*2112 + kw*32 + h*1024) at use
  const char* xb0 = (const char*)xsm[0] + (ps * 66 + l31) * 32 + l5 * 16;
  const char* xb1 = (const char*)xsm[1] + (ps * 66 + l31) * 32 + l5 * 16;

  f32x16 acc[4][2];
#pragma unroll
  for (int mf = 0; mf < 4; ++mf)
#pragma unroll
    for (int h = 0; h < 2; ++h)
#pragma unroll
      for (int q = 0; q < 16; ++q) acc[mf][h][q] = 0.f;

  // ---- staging macros (512 thr, 8192 B per round) ----
#define GLLL(cn)                                                               \
  _Pragma("unroll") for (int r = 0; r < 4; ++r) {                              \
    GLL16(wq + ((size_t)(b * 16 + (cn))) * 36864 + (r * 512 + t) * 8,          \
          &wsm[(r * 512 + t) * 8]);                                            \
  }
#define GLLH(cn)                                                               \
  _Pragma("unroll") for (int r = 0; r < 5; ++r) {                              \
    GLL16(wq + ((size_t)(b * 16 + (cn))) * 36864 + 16384 + (r * 512 + t) * 8,  \
          &wsm[16384 + (r * 512 + t) * 8]);                                    \
  }
#define GLLX(cn, nb)                                                           \
  _Pragma("unroll") for (int r = 0; r < 2; ++r) {                              \
    GLL16(xq + ((size_t)((b * 16 + (cn)) * 66 + r0)) * 1056 + (r * 512 + t) * 8, \
          &xsm[nb][(r * 512 + t) * 8]);                                        \
  }

  // inline frag read + 8 MFMAs for one tap
#define TAP(T, xbp)                                                            \
  {                                                                            \
    short8 A[4], Bv[2];                                                        \
    _Pragma("unroll") for (int mf = 0; mf < 4; ++mf)                           \
        A[mf] = *(const short8*)(aw + (T) * 8192 + mf * 1024);                 \
    _Pragma("unroll") for (int h = 0; h < 2; ++h)                              \
        Bv[h] = *(const short8*)((xbp) + ((T) / 3) * 2112 + ((T) % 3) * 32 +   \
                                 h * 1024);                                    \
    _Pragma("unroll") for (int h = 0; h < 2; ++h)                              \
        _Pragma("unroll") for (int mf = 0; mf < 4; ++mf)                       \
            acc[mf][h] = __builtin_amdgcn_mfma_f32_32x32x16_bf16(              \
                A[mf], Bv[h], acc[mf][h], 0, 0, 0);                            \
  }

#define SBAR __builtin_amdgcn_sched_barrier(0)
#define LGKM0 asm volatile("s_waitcnt lgkmcnt(0)" ::: "memory")
#define VM0 asm volatile("s_waitcnt vmcnt(0)" ::: "memory")
#define BAR __builtin_amdgcn_s_barrier()

  // prologue: stage c=0 fully (11 GLL rounds)
  GLLL(0); GLLH(0); GLLX(0, 0);
  VM0;
  BAR;
  SBAR;

  for (int c = 0; c < 16; ++c) {
    const char* xbp = (c & 1) ? xb1 : xb0;
    // ---- taps 0-3 from L half + x(c) ----
    TAP(0, xbp); TAP(1, xbp); TAP(2, xbp); TAP(3, xbp);
    LGKM0;  // my L/x reads done
    VM0;    // H(c) rounds (issued last half-step) drained -> visible after BAR
    SBAR;
    BAR;
    SBAR;
    if (c < 15) { GLLL(c + 1); GLLX(c + 1, (c & 1) ^ 1); }  // in flight over taps4-8
    // ---- taps 4-8 from H half ----
    TAP(4, xbp); TAP(5, xbp); TAP(6, xbp); TAP(7, xbp); TAP(8, xbp);
    LGKM0;  // my H reads done
    VM0;    // L(c+1)+x(c+1) drained -> visible after BAR
    SBAR;
    BAR;
    SBAR;
    if (c < 15) { GLLH(c + 1); }  // in flight over taps0-3 of c+1
  }

  // ---- fused epilogue: RMSNorm over channels + gamma*16 + SiLU ----
  // D frag: col(px) = lane&31, o-row = (q&3) + 8*(q>>2) + 4*(lane>>5)
#pragma unroll
  for (int h = 0; h < 2; ++h) {
    float pssum = 0.f;
#pragma unroll
    for (int mf = 0; mf < 4; ++mf)
#pragma unroll
      for (int q = 0; q < 16; ++q) {
        float v = acc[mf][h][q];
        pssum = fmaf(v, v, pssum);
      }
    int px = ps * 64 + h * 32 + l31;
    redl[(oh * 2 + l5) * 256 + px] = pssum;
  }
  __syncthreads();
  if (t < 256) {
    float ssum = redl[t] + redl[256 + t] + redl[512 + t] + redl[768 + t];
    invs[t] = 16.0f / fmaxf(sqrtf(ssum), 1e-12f);
  }
  __syncthreads();
  float iv2[2];
#pragma unroll
  for (int h = 0; h < 2; ++h) iv2[h] = invs[ps * 64 + h * 32 + l31];

#pragma unroll
  for (int mf = 0; mf < 4; ++mf)
#pragma unroll
    for (int q = 0; q < 16; ++q) {
      int o = oh * 128 + mf * 32 + (q & 3) + 8 * (q >> 2) + 4 * l5;
      float g = gsm[o];
      size_t ob = ((size_t)b * 256 + o) * 64 + (r0 + ps);
#pragma unroll
      for (int h = 0; h < 2; ++h) {
        float v = acc[mf][h][q] * iv2[h] * g;
        float sg = 1.0f / (1.0f + expf(-v));
        out[ob * 64 + h * 32 + l31] = v * sg;
      }
    }
#undef GLLL
#undef GLLH
#undef GLLX
#undef TAP
#undef SBAR
#undef LGKM0
#undef VM0
#undef BAR
}

extern "C" void kernel_launch(void* const* d_in, const int* in_sizes, int n_in,
                              void* d_out, int out_size, void* d_ws, size_t ws_size,
                              hipStream_t stream) {
  const float* x = (const float*)d_in[0];
  const float* mod = (const float*)d_in[1];
  const float* kmod = (const float*)d_in[2];
  const float* weights = (const float*)d_in[3];
  const float* gamma = (const float*)d_in[4];
  float* out = (float*)d_out;

  // ws layout: xq FIRST (35,684,352 B) so conv's uniform x-stage rounds may
  // overrun harmlessly into wq; wq (18,874,368 B) after. Total ~54.6 MB.
  unsigned short* xq = (unsigned short*)d_ws;
  unsigned short* wq = (unsigned short*)((char*)d_ws + 35684352);

  wprep<<<512, 256, 0, stream>>>(mod, kmod, weights, wq);
  xprep<<<16 * 16 * 66, 256, 0, stream>>>(x, xq);
  conv_fused<<<256, 512, 0, stream>>>(xq, wq, gamma, out);
}

// Round 16
// 120.424 us; speedup vs baseline: 2.2359x; 1.0039x over previous
//
#include <hip/hip_runtime.h>
#include <math.h>

// B=16, C_IN=256, C_OUT=256, H=W=64, K=3, NK=2
// weights: [2][256][256][3][3]; bank stride 589824 floats; per-o stride 2304.
//
// Pipeline (3 kernels):
//  1. wprep: combined+modulated+demod bf16 weights -> wq, 32x32-MFMA LDS image
//     per (b,c16): [tap9][oh2][mf4][lane64][e8] (36864 ush), A-frag:
//     o = oh*128 + mf*32 + (lane&31), i = c*16 + (lane>>5)*8 + e.
//  2. xprep: x -> bf16 xq [b][c16][rowp66][colp66][io2][e8], halo zeros,
//     BANK-SWIZZLED: granule (colp,io) stored at (colp, io^(colp&1)).
//  3. conv_fused: implicit GEMM mfma_f32_32x32x16_bf16 (9 taps = 9 MFMAs).
//     Block 512 thr (8 waves, 2/SIMD) = 256 o x 4 rows x 64 px; wave =
//     (oh,ps) 128o x 64px, mf4 x nf2, acc 128 (AGPR). P/Q one-tap-ahead
//     fragment prefetch: DSRD(tap+1) issued BEFORE MFMAs of tap (counted
//     lgkm from compiler) -> LDS pipe overlaps MFMA pipe. setprio around
//     MFMA clusters. A staged in 2 rolling halves, x double-buffered,
//     vmcnt(0)-drain-before-barrier gating (race-free, drains pre-covered).
//     Epilogue: fused channel RMSNorm * gamma * 16 + SiLU.

typedef __attribute__((ext_vector_type(8))) short short8;
typedef __attribute__((ext_vector_type(16))) float f32x16;

#define GLL16(src, dst)                                                       \
  __builtin_amdgcn_global_load_lds(                                           \
      (const __attribute__((address_space(1))) unsigned int*)(src),           \
      (__attribute__((address_space(3))) unsigned int*)(dst), 16, 0, 0)

static __device__ __forceinline__ unsigned short f2bf(float v) {
  union { float f; unsigned u; } u;
  u.f = v;
  unsigned r = u.u + 0x7FFF + ((u.u >> 16) & 1);  // RNE
  return (unsigned short)(r >> 16);
}

// ---------------------------------------------------------------------------
// Kernel 1: fused weight prep. Grid 512 = b(16) x oq(32 o-octets), 256 thr.
// ---------------------------------------------------------------------------
__global__ __launch_bounds__(256) void wprep(
    const float* __restrict__ mod, const float* __restrict__ kmod,
    const float* __restrict__ weights, unsigned short* __restrict__ wq) {
  int blk = blockIdx.x;  // b*32 + oq
  int b = blk >> 5, oq = blk & 31;
  int t = threadIdx.x;
  int o_l = t >> 5, its = t & 31;
  int o = oq * 8 + o_l;

  float k0 = kmod[b * 2 + 0], k1 = kmod[b * 2 + 1];
  float mx = fmaxf(k0, k1);
  float e0 = expf(k0 - mx), e1 = expf(k1 - mx);
  float ai = 1.0f / (e0 + e1);
  float a0 = e0 * ai, a1 = e1 * ai;

  float wv[9][8];  // [j][e]
  float s = 0.0f;
  const float* w0 = &weights[((size_t)o * 256 + its * 8) * 9];
  const float* w1 = w0 + 589824;
#pragma unroll
  for (int e = 0; e < 8; ++e) {
    float f = mod[b * 256 + its * 8 + e] + 1.0f;
#pragma unroll
    for (int j = 0; j < 9; ++j) {
      float v = (a0 * w0[e * 9 + j] + a1 * w1[e * 9 + j]) * f;
      wv[j][e] = v;
      s = fmaf(v, v, s);
    }
  }

  __shared__ float red[8][32];
  __shared__ float scl[8];
  red[o_l][its] = s;
  __syncthreads();
  if (t < 8) {
    float tot = 0.0f;
#pragma unroll
    for (int k = 0; k < 32; ++k) tot += red[t][k];
    scl[t] = rsqrtf(fmaxf(tot, 1e-8f));
  }
  __syncthreads();
  float sc = scl[o_l];

  int c = its >> 1, io = its & 1;
  int oh = o >> 7, mf = (o >> 5) & 3;
  int lane2 = (o & 31) + io * 32;
  // chunk [tap9][oh2][mf4][lane64][e8] ush per (b,c)
  size_t cbase = ((size_t)(b * 16 + c)) * 36864 + oh * 2048 + mf * 512 + lane2 * 8;
#pragma unroll
  for (int j = 0; j < 9; ++j) {
    short8 pk;
#pragma unroll
    for (int e = 0; e < 8; ++e) pk[e] = (short)f2bf(wv[j][e] * sc);
    *(short8*)(wq + cbase + j * 4096) = pk;
  }
}

// ---------------------------------------------------------------------------
// Kernel 2: x prep -> bf16 xq, bank-swizzled: granule (colp,io)->(colp,io^(colp&1)).
// ---------------------------------------------------------------------------
__global__ __launch_bounds__(256) void xprep(
    const float* __restrict__ x, unsigned short* __restrict__ xq) {
  int blk = blockIdx.x;  // (b*16 + c)*66 + rowp
  int rowp = blk % 66;
  int bc = blk / 66;
  int b = bc >> 4, c = bc & 15;
  int t = threadIdx.x;
  size_t obase = (size_t)blk * 1056;

  if (rowp == 0 || rowp == 65) {
    for (int idx = t; idx < 1056; idx += 256) xq[obase + idx] = 0;
    return;
  }
  __shared__ __align__(16) unsigned short xs2[1056];
  int row = rowp - 1;
  for (int idx = t; idx < 1056; idx += 256) xs2[idx] = 0;
  __syncthreads();
#pragma unroll
  for (int k = 0; k < 4; ++k) {
    int idx = t + k * 256;  // 0..1023
    int il = idx >> 6, col = idx & 63;
    float v = x[(((size_t)b * 256 + c * 16 + il) * 64 + row) * 64 + col];
    xs2[(col + 1) * 16 + il] = f2bf(v);
  }
  __syncthreads();
  if (t < 132) {
    int colp = t >> 1, io = t & 1;
    int d = colp * 2 + (io ^ (colp & 1));  // bank swizzle
    *(short8*)(xq + obase + (size_t)d * 8) = *(const short8*)&xs2[t * 8];
  }
}

// ---------------------------------------------------------------------------
// Kernel 3: fused conv + RMSNorm + SiLU. Grid 256 (XCD-clustered), 512 thr.
// ---------------------------------------------------------------------------
__global__ __launch_bounds__(512, 2) void conv_fused(
    const unsigned short* __restrict__ xq, const unsigned short* __restrict__ wq,
    const float* __restrict__ gamma, float* __restrict__ out) {
  __shared__ __align__(16) unsigned short wsm[36864];    // [tap][oh][mf][lane][e]
  __shared__ __align__(16) unsigned short xsm[2][8192];  // 16384 B each
  __shared__ float redl[1024];                           // [adder4][px256]
  __shared__ float invs[256];
  __shared__ float gsm[256];

  int bid = blockIdx.x;
  int xcd = bid & 7;
  int kk = bid >> 3;            // 0..31
  int b = xcd * 2 + (kk >> 4);  // 2 batches per XCD
  int rt = kk & 15;             // 4-row tile
  int r0 = rt * 4;

  int t = threadIdx.x;
  int w = t >> 6, lane = t & 63;
  int oh = w & 1, ps = w >> 1;  // wave = (oh: 128-o half, ps: row slot 0..3)
  int l31 = lane & 31, l5 = lane >> 5;

  if (t < 256) gsm[t] = gamma[t];

  // A base: + imm(tap*8192 + mf*1024) at use (contiguous 1KB/wave: no conflict)
  const char* aw = (const char*)wsm + oh * 4096 + lane * 16;
  // B byte offsets per tap, swizzle folded in: addr = xsm[buf] + boffs[T] + h*1024
  int boffs[9];
#pragma unroll
  for (int T = 0; T < 9; ++T) {
    int kh = T / 3, kw = T % 3;
    int base = (ps + kh) * 2112 + (l31 + kw) * 32 + l5 * 16;
    boffs[T] = base ^ ((((l31 + kw) & 1)) << 4);  // matches xprep swizzle
  }

  f32x16 acc[4][2];
#pragma unroll
  for (int mf = 0; mf < 4; ++mf)
#pragma unroll
    for (int h = 0; h < 2; ++h)
#pragma unroll
      for (int q = 0; q < 16; ++q) acc[mf][h][q] = 0.f;

  // ---- staging macros (512 thr, 8192 B per round) ----
#define GLLL(cn)                                                               \
  _Pragma("unroll") for (int r = 0; r < 4; ++r) {                              \
    GLL16(wq + ((size_t)(b * 16 + (cn))) * 36864 + (r * 512 + t) * 8,          \
          &wsm[(r * 512 + t) * 8]);                                            \
  }
#define GLLH(cn)                                                               \
  _Pragma("unroll") for (int r = 0; r < 5; ++r) {                              \
    GLL16(wq + ((size_t)(b * 16 + (cn))) * 36864 + 16384 + (r * 512 + t) * 8,  \
          &wsm[16384 + (r * 512 + t) * 8]);                                    \
  }
#define GLLX(cn, nb)                                                           \
  _Pragma("unroll") for (int r = 0; r < 2; ++r) {                              \
    GLL16(xq + ((size_t)((b * 16 + (cn)) * 66 + r0)) * 1056 + (r * 512 + t) * 8, \
          &xsm[nb][(r * 512 + t) * 8]);                                        \
  }

  short8 PA[4], PB[2], QA[4], QB[2];

#define DSRD(SA, SB, T, xsb_)                                                  \
  {                                                                            \
    _Pragma("unroll") for (int mf = 0; mf < 4; ++mf)                           \
        SA[mf] = *(const short8*)(aw + (T) * 8192 + mf * 1024);                \
    _Pragma("unroll") for (int h = 0; h < 2; ++h)                              \
        SB[h] = *(const short8*)((xsb_) + boffs[T] + h * 1024);                \
  }

#define MFMA8(SA, SB)                                                          \
  {                                                                            \
    __builtin_amdgcn_s_setprio(1);                                             \
    _Pragma("unroll") for (int h = 0; h < 2; ++h)                              \
        _Pragma("unroll") for (int mf = 0; mf < 4; ++mf)                       \
            acc[mf][h] = __builtin_amdgcn_mfma_f32_32x32x16_bf16(              \
                SA[mf], SB[h], acc[mf][h], 0, 0, 0);                           \
    __builtin_amdgcn_s_setprio(0);                                             \
  }

#define SBAR __builtin_amdgcn_sched_barrier(0)
#define LGKM0 asm volatile("s_waitcnt lgkmcnt(0)" ::: "memory")
#define VM0 asm volatile("s_waitcnt vmcnt(0)" ::: "memory")
#define BAR __builtin_amdgcn_s_barrier()

  const char* xs0 = (const char*)xsm[0];
  const char* xs1 = (const char*)xsm[1];

  // prologue: stage c=0 fully; preload P = tap0
  GLLL(0); GLLH(0); GLLX(0, 0);
  VM0;
  BAR;
  SBAR;
  DSRD(PA, PB, 0, xs0);
  SBAR;

  for (int c = 0; c < 16; ++c) {
    const char* xsb = (c & 1) ? xs1 : xs0;
    const char* xsn = (c & 1) ? xs0 : xs1;
    // ---- taps 0-3 from L half; one-tap-ahead prefetch ----
    DSRD(QA, QB, 1, xsb); SBAR; MFMA8(PA, PB);
    DSRD(PA, PB, 2, xsb); SBAR; MFMA8(QA, QB);
    DSRD(QA, QB, 3, xsb); SBAR; MFMA8(PA, PB);
    SBAR; MFMA8(QA, QB);
    LGKM0;  // all my L/x reads done
    VM0;    // my H(c) GLL rounds (issued last c-step) drained
    SBAR;
    BAR;    // H(c) visible to all; L region free for overwrite
    SBAR;
    if (c < 15) { GLLL(c + 1); GLLX(c + 1, (c & 1) ^ 1); }
    DSRD(PA, PB, 4, xsb); SBAR;
    // ---- taps 4-8 from H half ----
    DSRD(QA, QB, 5, xsb); SBAR; MFMA8(PA, PB);
    DSRD(PA, PB, 6, xsb); SBAR; MFMA8(QA, QB);
    DSRD(QA, QB, 7, xsb); SBAR; MFMA8(PA, PB);
    DSRD(PA, PB, 8, xsb); SBAR; MFMA8(QA, QB);
    SBAR; MFMA8(PA, PB);
    LGKM0;  // all my H reads done
    VM0;    // my L(c+1)+x(c+1) rounds drained
    SBAR;
    BAR;    // L(c+1)/x(c+1) visible; H region free for overwrite
    SBAR;
    if (c < 15) {
      GLLH(c + 1);
      DSRD(PA, PB, 0, xsn);  // preload tap0 of c+1 (L(c+1) now visible)
      SBAR;
    }
  }

  // ---- fused epilogue: RMSNorm over channels + gamma*16 + SiLU ----
  // D frag: col(px) = lane&31, o-row = (q&3) + 8*(q>>2) + 4*(lane>>5)
#pragma unroll
  for (int h = 0; h < 2; ++h) {
    float pssum = 0.f;
#pragma unroll
    for (int mf = 0; mf < 4; ++mf)
#pragma unroll
      for (int q = 0; q < 16; ++q) {
        float v = acc[mf][h][q];
        pssum = fmaf(v, v, pssum);
      }
    int px = ps * 64 + h * 32 + l31;
    redl[(oh * 2 + l5) * 256 + px] = pssum;
  }
  __syncthreads();
  if (t < 256) {
    float ssum = redl[t] + redl[256 + t] + redl[512 + t] + redl[768 + t];
    invs[t] = 16.0f / fmaxf(sqrtf(ssum), 1e-12f);
  }
  __syncthreads();
  float iv2[2];
#pragma unroll
  for (int h = 0; h < 2; ++h) iv2[h] = invs[ps * 64 + h * 32 + l31];

#pragma unroll
  for (int mf = 0; mf < 4; ++mf)
#pragma unroll
    for (int q = 0; q < 16; ++q) {
      int o = oh * 128 + mf * 32 + (q & 3) + 8 * (q >> 2) + 4 * l5;
      float g = gsm[o];
      size_t ob = ((size_t)b * 256 + o) * 64 + (r0 + ps);
#pragma unroll
      for (int h = 0; h < 2; ++h) {
        float v = acc[mf][h][q] * iv2[h] * g;
        float sg = 1.0f / (1.0f + expf(-v));
        out[ob * 64 + h * 32 + l31] = v * sg;
      }
    }
#undef GLLL
#undef GLLH
#undef GLLX
#undef DSRD
#undef MFMA8
#undef SBAR
#undef LGKM0
#undef VM0
#undef BAR
}

extern "C" void kernel_launch(void* const* d_in, const int* in_sizes, int n_in,
                              void* d_out, int out_size, void* d_ws, size_t ws_size,
                              hipStream_t stream) {
  const float* x = (const float*)d_in[0];
  const float* mod = (const float*)d_in[1];
  const float* kmod = (const float*)d_in[2];
  const float* weights = (const float*)d_in[3];
  const float* gamma = (const float*)d_in[4];
  float* out = (float*)d_out;

  // ws layout: xq FIRST (35,684,352 B) so conv's uniform x-stage rounds may
  // overrun harmlessly into wq; wq (18,874,368 B) after. Total ~54.6 MB.
  unsigned short* xq = (unsigned short*)d_ws;
  unsigned short* wq = (unsigned short*)((char*)d_ws + 35684352);

  wprep<<<512, 256, 0, stream>>>(mod, kmod, weights, wq);
  xprep<<<16 * 16 * 66, 256, 0, stream>>>(x, xq);
  conv_fused<<<256, 512, 0, stream>>>(xq, wq, gamma, out);
}